// Round 10
// baseline (145.072 us; speedup 1.0000x reference)
//
#include <hip/hip_runtime.h>

#define B_DIM   2048
#define IN_DIM  4096
#define OUT_DIM 4096
#define FAN     64

// R10 = R9's pipeline + bank-group-balanced gather order.
//  Evidence: R3 (2-barrier) == R9 (1-barrier dbuf) == 52.5-52.9 us -> DS pipe
//  is the invariant wall at ~30.8 cyc per random-gather b128; measured bank
//  conflicts are 34K cyc/CU (27% of wall). Fix: each thread counting-sorts its
//  64 (idx,w) by bank-group (idx&7) with per-lane phase rotation so that at
//  gather slot j, lane l reads group (j+l)&7 -> exactly 8 lanes per 4-bank
//  group per instruction -> structurally conflict-free (residual: bucket-size
//  variance only). Sort runs once per block in LDS scratch that time-shares
//  with the tile double-buffer (no extra global memory).
//  Item format: u32 = (bf16(w) << 16) | (idx << 4). addr = it & 0xffff;
//  w = __uint_as_float(it & 0xffff0000) — bf16 high-bits trick, zero unpack.
//  Spill hygiene (R2/R4/R7): __launch_bounds__(512,1); items loaded once,
//  never mutated; all small arrays statically unrolled.

typedef float v2f __attribute__((ext_vector_type(2)));

__device__ __forceinline__ unsigned bf16_rne(float f) {
    unsigned u = __float_as_uint(f);
    return (u + 0x7fffu + ((u >> 16) & 1u)) >> 16;   // round-to-nearest-even bf16
}

// ---------------- Phase 1: pack fp32 -> bf16 8-row cells ----------------
__global__ __launch_bounds__(256) void pack_kernel(
    const float* __restrict__ input, uint4* __restrict__ wsp)
{
    const int idx = blockIdx.x * 256 + threadIdx.x;   // [0, 524288): 2 cells each
    const int t   = idx >> 11;                        // tile [0,256)
    const int c0  = (idx & 2047) << 1;                // column pair [0,4096)

    const float* p = input + (size_t)t * 8 * IN_DIM + c0;
    const float2 r0 = *reinterpret_cast<const float2*>(p + 0 * IN_DIM);
    const float2 r1 = *reinterpret_cast<const float2*>(p + 1 * IN_DIM);
    const float2 r2 = *reinterpret_cast<const float2*>(p + 2 * IN_DIM);
    const float2 r3 = *reinterpret_cast<const float2*>(p + 3 * IN_DIM);
    const float2 r4 = *reinterpret_cast<const float2*>(p + 4 * IN_DIM);
    const float2 r5 = *reinterpret_cast<const float2*>(p + 5 * IN_DIM);
    const float2 r6 = *reinterpret_cast<const float2*>(p + 6 * IN_DIM);
    const float2 r7 = *reinterpret_cast<const float2*>(p + 7 * IN_DIM);

    uint4 a, b;
    a.x = bf16_rne(r0.x) | (bf16_rne(r1.x) << 16);
    a.y = bf16_rne(r2.x) | (bf16_rne(r3.x) << 16);
    a.z = bf16_rne(r4.x) | (bf16_rne(r5.x) << 16);
    a.w = bf16_rne(r6.x) | (bf16_rne(r7.x) << 16);
    b.x = bf16_rne(r0.y) | (bf16_rne(r1.y) << 16);
    b.y = bf16_rne(r2.y) | (bf16_rne(r3.y) << 16);
    b.z = bf16_rne(r4.y) | (bf16_rne(r5.y) << 16);
    b.w = bf16_rne(r6.y) | (bf16_rne(r7.y) << 16);

    uint4* q = wsp + (size_t)t * IN_DIM + c0;
    q[0] = a;
    q[1] = b;
}

// ---------------- shared gather body (BASE = compile-time buffer offset) ----
template <unsigned BASE>
__device__ __forceinline__ void gather_tile(
    const char* ldsb, const unsigned* items, float bv, float* op)
{
    v2f a01 = {0.f, 0.f}, a23 = {0.f, 0.f}, a45 = {0.f, 0.f}, a67 = {0.f, 0.f};
    #pragma unroll
    for (int jj = 0; jj < FAN / 2; ++jj) {
        const unsigned it0 = items[2*jj+0];
        const unsigned it1 = items[2*jj+1];
        const uint4 g0 = *reinterpret_cast<const uint4*>(ldsb + BASE + (it0 & 0xffffu));
        const uint4 g1 = *reinterpret_cast<const uint4*>(ldsb + BASE + (it1 & 0xffffu));
        {
            const float wf = __uint_as_float(it0 & 0xffff0000u);   // bf16 -> f32
            const v2f w2 = {wf, wf};
            v2f v;
            v.x = __uint_as_float(g0.x << 16);
            v.y = __uint_as_float(g0.x & 0xffff0000u);
            a01 = __builtin_elementwise_fma(v, w2, a01);
            v.x = __uint_as_float(g0.y << 16);
            v.y = __uint_as_float(g0.y & 0xffff0000u);
            a23 = __builtin_elementwise_fma(v, w2, a23);
            v.x = __uint_as_float(g0.z << 16);
            v.y = __uint_as_float(g0.z & 0xffff0000u);
            a45 = __builtin_elementwise_fma(v, w2, a45);
            v.x = __uint_as_float(g0.w << 16);
            v.y = __uint_as_float(g0.w & 0xffff0000u);
            a67 = __builtin_elementwise_fma(v, w2, a67);
        }
        {
            const float wf = __uint_as_float(it1 & 0xffff0000u);
            const v2f w2 = {wf, wf};
            v2f v;
            v.x = __uint_as_float(g1.x << 16);
            v.y = __uint_as_float(g1.x & 0xffff0000u);
            a01 = __builtin_elementwise_fma(v, w2, a01);
            v.x = __uint_as_float(g1.y << 16);
            v.y = __uint_as_float(g1.y & 0xffff0000u);
            a23 = __builtin_elementwise_fma(v, w2, a23);
            v.x = __uint_as_float(g1.z << 16);
            v.y = __uint_as_float(g1.z & 0xffff0000u);
            a45 = __builtin_elementwise_fma(v, w2, a45);
            v.x = __uint_as_float(g1.w << 16);
            v.y = __uint_as_float(g1.w & 0xffff0000u);
            a67 = __builtin_elementwise_fma(v, w2, a67);
        }
    }
    op[0 * OUT_DIM] = a01.x + bv;
    op[1 * OUT_DIM] = a01.y + bv;
    op[2 * OUT_DIM] = a23.x + bv;
    op[3 * OUT_DIM] = a23.y + bv;
    op[4 * OUT_DIM] = a45.x + bv;
    op[5 * OUT_DIM] = a45.y + bv;
    op[6 * OUT_DIM] = a67.x + bv;
    op[7 * OUT_DIM] = a67.y + bv;
}

__device__ __forceinline__ void dma_tile(const uint4* __restrict__ wsp,
                                         uint4* lds, int tile, int tid, int buf)
{
    const uint4* src = wsp + (size_t)tile * IN_DIM + tid;
    uint4*       dst = lds + buf * IN_DIM + tid;
    #pragma unroll
    for (int it = 0; it < 8; ++it) {
        __builtin_amdgcn_global_load_lds(
            (const __attribute__((address_space(1))) unsigned*)(src + it * 512),
            (__attribute__((address_space(3))) unsigned*)(dst + it * 512),
            16, 0, 0);
    }
}

// ---------------- Phase 2: balanced double-buffered gather ----------------
#define SCRATCH_STRIDE 264   // bytes/thread: 8B-aligned, 66 words -> bank-rotating
#define SMEM_BYTES     (512 * SCRATCH_STRIDE > 131072 ? 512 * SCRATCH_STRIDE : 131072)

__global__ __launch_bounds__(512, 1) void condensed_kernel(
    const uint4* __restrict__ wsp,
    const float* __restrict__ weight,
    const float* __restrict__ bias,
    const int*   __restrict__ mask,
    float*       __restrict__ out)
{
    extern __shared__ __align__(16) unsigned char smem[];  // 135168 B, time-shared
    uint4* lds = reinterpret_cast<uint4*>(smem);           // tile dbuf (2 x 64 KB)

    const int tid   = threadIdx.x;                    // [0,512)
    const int o     = blockIdx.y * 512 + tid;
    const int bseg  = blockIdx.x * 64;                // 64 batch rows per block
    const int tbase = bseg >> 3;                      // 8 tiles per block

    // ---- load (idx,w) -> combined u32, counting-sort by bank-group with
    //      per-lane phase rotation, via LDS scratch (pre-staging) ----
    unsigned items[FAN];
    {
        unsigned raw[FAN];
        const int4*   mv = reinterpret_cast<const int4*>(mask)     + o * (FAN / 4);
        const float4* wp = reinterpret_cast<const float4*>(weight) + o * (FAN / 4);
        #pragma unroll
        for (int j = 0; j < FAN / 4; ++j) {
            int4   m4 = mv[j];
            float4 w4 = wp[j];
            raw[4*j+0] = ((unsigned)m4.x << 4) | (bf16_rne(w4.x) << 16);
            raw[4*j+1] = ((unsigned)m4.y << 4) | (bf16_rne(w4.y) << 16);
            raw[4*j+2] = ((unsigned)m4.z << 4) | (bf16_rne(w4.z) << 16);
            raw[4*j+3] = ((unsigned)m4.w << 4) | (bf16_rne(w4.w) << 16);
        }

        // counts per bank-group g = idx&7 = (raw>>4)&7
        int c[8] = {0,0,0,0,0,0,0,0};
        #pragma unroll
        for (int k = 0; k < FAN; ++k) {
            const unsigned g = (raw[k] >> 4) & 7u;
            #pragma unroll
            for (int gg = 0; gg < 8; ++gg) c[gg] += (g == (unsigned)gg);
        }
        int off[8];
        off[0] = 0;
        #pragma unroll
        for (int g = 1; g < 8; ++g) off[g] = off[g-1] + c[g-1];

        // this lane's phase start = offset of group (tid&7) in its own sorted list
        const int ph = tid & 7;
        int s = 0;
        #pragma unroll
        for (int g = 0; g < 8; ++g) s = (ph == g) ? off[g] : s;

        // placement: group-sorted position, rotated by -s, scattered to LDS
        unsigned char* scratch = smem + tid * SCRATCH_STRIDE;
        int r[8] = {0,0,0,0,0,0,0,0};
        #pragma unroll
        for (int k = 0; k < FAN; ++k) {
            const unsigned g = (raw[k] >> 4) & 7u;
            int p = 0;
            #pragma unroll
            for (int gg = 0; gg < 8; ++gg) {
                const int m = (g == (unsigned)gg);
                p = m ? (off[gg] + r[gg]) : p;
                r[gg] += m;
            }
            const int pos = (p - s) & 63;
            *reinterpret_cast<unsigned*>(scratch + pos * 4) = raw[k];
        }
        // readback own region (same-thread DS ordering; compiler emits lgkmcnt)
        #pragma unroll
        for (int k = 0; k < FAN / 2; ++k) {
            const uint2 t = *reinterpret_cast<const uint2*>(scratch + k * 8);
            items[2*k+0] = t.x;
            items[2*k+1] = t.y;
        }
    }
    const float bv = bias[o];
    __syncthreads();                                  // scratch dead before DMA

    const char* ldsb = reinterpret_cast<const char*>(lds);

    // ---- prologue: DMA tile 0 -> buf0 ----
    dma_tile(wsp, lds, tbase, tid, 0);
    __syncthreads();                                  // buf0 resident

    for (int hp = 0; hp < 4; ++hp) {                  // 4 x (stage A + stage B)
        const int t0 = hp * 2;

        // ==== stage A: prefetch tile t0+1 -> buf1, compute buf0 ====
        dma_tile(wsp, lds, tbase + t0 + 1, tid, 1);
        gather_tile<0u>(ldsb, items, bv,
                        out + (size_t)(bseg + 8 * t0) * OUT_DIM + o);
        __syncthreads();   // buf0 free; prefetch (issued a compute-phase ago) drained

        // ==== stage B: prefetch tile t0+2 -> buf0, compute buf1 ====
        if (hp < 3) {
            dma_tile(wsp, lds, tbase + t0 + 2, tid, 0);
        }
        gather_tile<65536u>(ldsb, items, bv,
                            out + (size_t)(bseg + 8 * t0 + 8) * OUT_DIM + o);
        __syncthreads();   // buf1 free; prefetch drained
    }
}

extern "C" void kernel_launch(void* const* d_in, const int* in_sizes, int n_in,
                              void* d_out, int out_size, void* d_ws, size_t ws_size,
                              hipStream_t stream) {
    const float* input  = (const float*)d_in[0];
    const float* weight = (const float*)d_in[1];
    const float* bias   = (const float*)d_in[2];
    const int*   mask   = (const int*)d_in[3];
    float*       out    = (float*)d_out;
    uint4*       wsp    = (uint4*)d_ws;               // 16 MiB (proven available)

    pack_kernel<<<2048, 256, 0, stream>>>(input, wsp);

    // 135168 B dynamic LDS opt-in (host-side, idempotent, capture-safe).
    hipFuncSetAttribute(reinterpret_cast<const void*>(condensed_kernel),
                        hipFuncAttributeMaxDynamicSharedMemorySize, SMEM_BYTES);
    dim3 grid(32, 8);    // 256 blocks, 512 thr: exactly 1 block/CU
    condensed_kernel<<<grid, 512, SMEM_BYTES, stream>>>(wsp, weight, bias, mask, out);
}